// Round 11
// baseline (256.414 us; speedup 1.0000x reference)
//
#include <hip/hip_runtime.h>
#include <hip/hip_bf16.h>

// B=32, C=32, H=W=256, regions 4x4 of 64x64.
// Round 11: three streaming passes.
//  1) stats_partial: per-(b,c) plane sums (unchanged, proven).
//  2) norm_write: finalize + normalize + PReLU + bf16, writes y in a
//     conv-ready pre-swizzled [b][p][row][col][ic] layout (128 MB).
//  3) conv_dma: stages y tiles via global_load_lds width=16 (no VGPR
//     round-trip, no staging VALU), then the proven MFMA compute phase.

#define EPS 1e-5f

typedef float f32x4 __attribute__((ext_vector_type(4)));
typedef __bf16 bf16x8 __attribute__((ext_vector_type(8)));
typedef short short8 __attribute__((ext_vector_type(8)));

__device__ inline short f2bf(float f) {
  union { __hip_bfloat16 h; short s; } u;
  u.h = __float2bfloat16(f);
  return u.s;
}

__device__ inline void dma16(const void* g, void* l) {
  __builtin_amdgcn_global_load_lds(
      (const __attribute__((address_space(1))) unsigned int*)g,
      (__attribute__((address_space(3))) unsigned int*)l, 16, 0, 0);
}

// ---------------- Kernel 1: per-(b,c) plane stats, contiguous sweep ----------
__global__ __launch_bounds__(256) void stats_partial(
    const float* __restrict__ x, float* __restrict__ ws_sum,
    float* __restrict__ ws_sq) {
  int plane = blockIdx.x;            // b*32 + c
  const float* base = x + (size_t)plane * 65536;
  int t = threadIdx.x;
  float s[4] = {0.f, 0.f, 0.f, 0.f}, q[4] = {0.f, 0.f, 0.f, 0.f};
#pragma unroll
  for (int R = 0; R < 4; ++R) {
#pragma unroll
    for (int ii = 0; ii < 16; ++ii) {
      int idx4 = (R * 16 + ii) * 256 + t;     // float4 index
      float4 v = *reinterpret_cast<const float4*>(base + (size_t)idx4 * 4);
      s[R] += (v.x + v.y) + (v.z + v.w);
      q[R] += (v.x * v.x + v.y * v.y) + (v.z * v.z + v.w * v.w);
    }
  }
#pragma unroll
  for (int R = 0; R < 4; ++R) {
#pragma unroll
    for (int off = 8; off; off >>= 1) {
      s[R] += __shfl_down(s[R], off);
      q[R] += __shfl_down(q[R], off);
    }
  }
  __shared__ float red[2][4][4][4];  // [s|q][wave][Cc][R]
  int lane = t & 63, wv = t >> 6;
  if ((lane & 15) == 0) {
    int Cc = lane >> 4;
#pragma unroll
    for (int R = 0; R < 4; ++R) {
      red[0][wv][Cc][R] = s[R];
      red[1][wv][Cc][R] = q[R];
    }
  }
  __syncthreads();
  if (t < 16) {                      // t == p
    int R = t >> 2, Cc = t & 3;
    float S = 0.f, Q = 0.f;
#pragma unroll
    for (int w = 0; w < 4; ++w) {
      S += red[0][w][Cc][R];
      Q += red[1][w][Cc][R];
    }
    ws_sum[plane * 16 + t] = S;
    ws_sq[plane * 16 + t] = Q;
  }
}

// ---------------- Kernel 2: pack conv_w into MFMA A-fragments ----------------
__global__ __launch_bounds__(256) void weights_prep(
    const float* __restrict__ conv_w, unsigned short* __restrict__ wfrag) {
  int idx = blockIdx.x * 256 + threadIdx.x;
  if (idx >= 18 * 64) return;
  int lane = idx & 63;
  int th = idx >> 6;                 // t*2 + h
  int t = th >> 1, h = th & 1;
  int dy = t / 3, dx = t - dy * 3;
  int oc = h * 16 + (lane & 15);
  int ic0 = (lane >> 4) * 8;
#pragma unroll
  for (int j = 0; j < 8; ++j) {
    float w = conv_w[((oc * 32 + ic0 + j) * 3 + dy) * 3 + dx];
    wfrag[(size_t)idx * 8 + j] = (unsigned short)f2bf(w);
  }
}

// ---------------- Kernel 3: finalize + normalize + PReLU -> y (bf16) --------
// 2048 blocks = (b reversed, p, quarter). y layout per (b,p) plane of
// 64x64x32: offset = (row*64 + col)*32 + slot*8 + k, slot=(s+(col>>1))&3,
// s = ic/8 — the conv LDS layout, so conv can DMA it linearly.
__global__ __launch_bounds__(256) void norm_write(
    const float* __restrict__ x, const float* __restrict__ ws_sum,
    const float* __restrict__ ws_sq, const float* __restrict__ gamma,
    const float* __restrict__ beta, const float* __restrict__ prelu_a,
    unsigned short* __restrict__ y) {
  __shared__ float abuf[64];
  int blk = blockIdx.x;              // qr = blk&3, p = (blk>>2)&15, b rev
  int qr = blk & 3;
  int p = (blk >> 2) & 15;
  int b = 31 - (blk >> 6);           // reverse-b: ride the L3 tail of stats
  int R = p >> 2, Cc = p & 3;
  int tid = threadIdx.x;

  if (tid < 32) {                    // local finalize for region p
    int c = tid;
    float S = 0.f, Q = 0.f;
#pragma unroll
    for (int bb = 0; bb < 32; ++bb) {
      int idx = (bb * 32 + c) * 16 + p;
      S += ws_sum[idx];
      Q += ws_sq[idx];
    }
    const float inv = 1.0f / 131072.0f;
    float mean = S * inv;
    float var = Q * inv - mean * mean;
    float rstd = rsqrtf(var + EPS);
    float a = rstd * gamma[c];
    abuf[c] = a;
    abuf[32 + c] = beta[c] - mean * a;
  }
  __syncthreads();

  int s = tid & 3;                   // ic-slice (low bits: write coalescing)
  int c4 = (tid >> 2) & 15;          // col-quad
  int rsub = tid >> 6;               // row within 4-row group
  int ic0 = s * 8;
  float a_r[8], b_r[8];
#pragma unroll
  for (int j = 0; j < 8; ++j) {
    a_r[j] = abuf[ic0 + j];
    b_r[j] = abuf[32 + ic0 + j];
  }
  float pa = prelu_a[0];

  unsigned short* yp = y + ((size_t)(b * 16 + p)) * 131072;
  const float* xb =
      x + ((size_t)(b * 32) * 65536) + (size_t)R * 64 * 256 + Cc * 64;

  for (int it = 0; it < 4; ++it) {
    int row = qr * 16 + it * 4 + rsub;        // 0..63
    const float* xr = xb + (size_t)ic0 * 65536 + row * 256 + c4 * 4;
    f32x4 v[8];
#pragma unroll
    for (int kk = 0; kk < 8; ++kk)
      v[kk] = *reinterpret_cast<const f32x4*>(xr + (size_t)kk * 65536);
#pragma unroll
    for (int j = 0; j < 4; ++j) {
      short8 pk;
#pragma unroll
      for (int kk = 0; kk < 8; ++kk) {
        float e = fmaf(a_r[kk], v[kk][j], b_r[kk]);
        e = e > 0.f ? e : pa * e;
        pk[kk] = f2bf(e);
      }
      int col = c4 * 4 + j;
      int slot = (s + (col >> 1)) & 3;
      *reinterpret_cast<short8*>(&yp[((size_t)row * 64 + col) * 32 + slot * 8]) =
          pk;
    }
  }
}

// ---------------- Kernel 4: DMA-staged MFMA conv ----------------------------
// block = (b, p, rt): 8 output rows. LDS [10][64][32] bf16 = 40960 B (DMA'd
// linearly from pre-swizzled y). 4 blocks/CU. Compute phase = r8's.
__global__ __launch_bounds__(256) void conv_dma(
    const unsigned short* __restrict__ y,
    const unsigned short* __restrict__ wfrag,
    const float* __restrict__ conv_b, float* __restrict__ out) {
  __shared__ short lds_y[10 * 64 * 32];  // 40960 B

  int blk0 = blockIdx.x;             // 4096 blocks; chunked XCD swizzle
  int blk = (blk0 & 7) * 512 + (blk0 >> 3);
  int rt = blk & 7;
  int p = (blk >> 3) & 15;
  int b = blk >> 7;
  int R = p >> 2, Cc = p & 3;
  int h0 = rt * 8;
  int tid = threadIdx.x;
  int lane = tid & 63;
  int wv = tid >> 6;

  // weight fragments + bias: issue first, in flight during DMA issue
  bf16x8 wf[18];
#pragma unroll
  for (int th = 0; th < 18; ++th) {
    short8 sv =
        *reinterpret_cast<const short8*>(wfrag + ((size_t)th * 64 + lane) * 8);
    wf[th] = __builtin_bit_cast(bf16x8, sv);
  }
  int l15 = lane & 15, l4 = lane >> 4;
  f32x4 bias0, bias1;
#pragma unroll
  for (int i = 0; i < 4; ++i) {
    bias0[i] = conv_b[l4 * 4 + i];
    bias1[i] = conv_b[16 + l4 * 4 + i];
  }

  // ---- DMA stage: 10 rows x 4 KB, 4 quarter-rows each; wave wv owns 10.
  const unsigned short* yp = y + ((size_t)(b * 16 + p)) * 131072;
  const short8 z8 = {0, 0, 0, 0, 0, 0, 0, 0};
#pragma unroll
  for (int k = 0; k < 10; ++k) {
    int i = wv * 10 + k;             // 0..39 (wave-uniform)
    int row = i >> 2, q = i & 3;
    int lr = h0 - 1 + row;           // region-local input row
    short* ldst = &lds_y[row * 2048 + q * 512];       // wave-uniform base
    if ((unsigned)lr < 64u) {
      const unsigned short* g =
          yp + (size_t)lr * 2048 + q * 512 + (size_t)lane * 8;
      dma16(g, ldst);                // HW scatters lane*16B
    } else {
      *reinterpret_cast<short8*>(&lds_y[row * 2048 + q * 512 + lane * 8]) = z8;
    }
  }
  __syncthreads();

  // ---- MFMA: each wave does 8 groups of (row r, 16-col block)
  for (int g = 0; g < 8; ++g) {
    int gi = wv * 8 + g;
    int r = gi >> 2;
    int c0 = (gi & 3) * 16;
    f32x4 acc0 = bias0, acc1 = bias1;
#pragma unroll
    for (int t9 = 0; t9 < 9; ++t9) {
      const int dy = t9 / 3, dx = t9 - dy * 3;
      int sr = r + dy;
      int col_in = c0 + l15 + dx - 1;     // -1..64 possible at edges
      int colc = col_in & 63;
      int slot = (l4 + (colc >> 1)) & 3;
      short8 sv = *reinterpret_cast<const short8*>(
          &lds_y[(sr * 64 + colc) * 32 + slot * 8]);
      if (dx == 0) {
        if (c0 == 0 && l15 == 0) sv = z8;     // col -1 -> zero pad
      }
      if (dx == 2) {
        if (c0 == 48 && l15 == 15) sv = z8;   // col 64 -> zero pad
      }
      bf16x8 bv = __builtin_bit_cast(bf16x8, sv);
      acc0 = __builtin_amdgcn_mfma_f32_16x16x32_bf16(wf[t9 * 2], bv, acc0, 0, 0, 0);
      acc1 = __builtin_amdgcn_mfma_f32_16x16x32_bf16(wf[t9 * 2 + 1], bv, acc1, 0, 0, 0);
    }
    int grow = R * 64 + h0 + r;
    int gcol = Cc * 64 + c0 + l15;
    float* ob = out + (size_t)b * 2097152 + (size_t)grow * 256 + gcol;
#pragma unroll
    for (int i = 0; i < 4; ++i) {
      ob[(size_t)(l4 * 4 + i) * 65536] = acc0[i];
      ob[(size_t)(16 + l4 * 4 + i) * 65536] = acc1[i];
    }
  }
}

extern "C" void kernel_launch(void* const* d_in, const int* in_sizes, int n_in,
                              void* d_out, int out_size, void* d_ws,
                              size_t ws_size, hipStream_t stream) {
  const float* x = (const float*)d_in[0];
  const float* gamma = (const float*)d_in[1];
  const float* beta = (const float*)d_in[2];
  const float* prelu_a = (const float*)d_in[3];
  const float* conv_w = (const float*)d_in[4];
  const float* conv_b = (const float*)d_in[5];
  float* out = (float*)d_out;

  float* ws = (float*)d_ws;
  float* ws_sum = ws;                          // 16384 floats
  float* ws_sq = ws + 16384;                   // 16384
  unsigned short* wfrag = (unsigned short*)(ws + 32768);   // 9216 shorts
  unsigned short* y = (unsigned short*)(ws + 40960);       // 67108864 shorts

  weights_prep<<<5, 256, 0, stream>>>(conv_w, wfrag);
  stats_partial<<<1024, 256, 0, stream>>>(x, ws_sum, ws_sq);
  norm_write<<<2048, 256, 0, stream>>>(x, ws_sum, ws_sq, gamma, beta, prelu_a,
                                       y);
  conv_dma<<<4096, 256, 0, stream>>>(y, wfrag, conv_b, out);
}

// Round 12
// 222.274 us; speedup vs baseline: 1.1536x; 1.1536x over previous
//
#include <hip/hip_runtime.h>
#include <hip/hip_bf16.h>

// B=32, C=32, H=W=256, regions 4x4 of 64x64.
// Round 12: two heavy passes.
//  1) stats_copy: reads x once; emits (a) per-(b,p,half,c) stats partials and
//     (b) raw bf16 copy xc in the conv LDS granule layout (pre-swizzled).
//  2) conv_dbuf: per-(b,p,16rows) block. Double-buffered LDS; tile t+1 is
//     DMA'd via global_load_lds (no staging VGPRs -> no spills) while tile t
//     computes; a short in-LDS norm+PReLU pass runs between computes.
// Granule layout: plane (b,p) of 64x64x32, addr16B(row,col,slot) =
// (row*64+col)*4 + slot, slot = (s + (col>>1)) & 3, s = ic>>3.

#define EPS 1e-5f

typedef float f32x4 __attribute__((ext_vector_type(4)));
typedef __bf16 bf16x8 __attribute__((ext_vector_type(8)));
typedef short short8 __attribute__((ext_vector_type(8)));

__device__ inline short f2bf(float f) {
  union { __hip_bfloat16 h; short s; } u;
  u.h = __float2bfloat16(f);
  return u.s;
}
__device__ inline float bf2f(short us) {
  unsigned v = (unsigned)(unsigned short)us << 16;
  return __builtin_bit_cast(float, v);
}
__device__ inline void dma16(const void* g, void* l) {
  __builtin_amdgcn_global_load_lds(
      (const __attribute__((address_space(1))) unsigned int*)g,
      (__attribute__((address_space(3))) unsigned int*)l, 16, 0, 0);
}

// ---------------- Kernel 1: stats partials + raw bf16 transposed copy -------
// 1024 blocks = (b, p, half h). 32 rows x 64 cols x 32 ic of region (b,p).
// Thread: s = tid&3 (ic-slice), c4 = (tid>>2)&15 (col-quad), rsub = tid>>6.
__global__ __launch_bounds__(256) void stats_copy(
    const float* __restrict__ x, float* __restrict__ ws_sum,
    float* __restrict__ ws_sq, unsigned short* __restrict__ xc) {
  int blk = blockIdx.x;
  int h = blk & 1;
  int p = (blk >> 1) & 15;
  int b = blk >> 5;
  int R = p >> 2, Cc = p & 3;
  int tid = threadIdx.x;
  int lane = tid & 63, wv = tid >> 6;

  int s = tid & 3;
  int c4 = (tid >> 2) & 15;
  int rsub = tid >> 6;
  int ic0 = s * 8;

  unsigned short* xcp = xc + ((size_t)(b * 16 + p)) * 131072;
  const float* xb =
      x + ((size_t)(b * 32 + ic0)) * 65536 + (size_t)R * 64 * 256 + Cc * 64;

  float sacc[8], qacc[8];
#pragma unroll
  for (int k = 0; k < 8; ++k) { sacc[k] = 0.f; qacc[k] = 0.f; }

  for (int it = 0; it < 8; ++it) {
    int row = h * 32 + it * 4 + rsub;        // region-local 0..63
    const float* xr = xb + (size_t)row * 256 + c4 * 4;
    f32x4 v[8];
#pragma unroll
    for (int k = 0; k < 8; ++k)
      v[k] = *reinterpret_cast<const f32x4*>(xr + (size_t)k * 65536);
#pragma unroll
    for (int k = 0; k < 8; ++k) {
      sacc[k] += (v[k][0] + v[k][1]) + (v[k][2] + v[k][3]);
      qacc[k] += (v[k][0] * v[k][0] + v[k][1] * v[k][1]) +
                 (v[k][2] * v[k][2] + v[k][3] * v[k][3]);
    }
#pragma unroll
    for (int j = 0; j < 4; ++j) {
      short8 pk;
#pragma unroll
      for (int k = 0; k < 8; ++k) pk[k] = f2bf(v[k][j]);
      int col = c4 * 4 + j;
      int slot = (s + (col >> 1)) & 3;
      *reinterpret_cast<short8*>(&xcp[((size_t)(row * 64 + col) * 4 + slot) * 8]) =
          pk;
    }
  }

  // reduce over c4 within wave (stride-4 lanes share s), then over waves
#pragma unroll
  for (int off = 4; off <= 32; off <<= 1) {
#pragma unroll
    for (int k = 0; k < 8; ++k) {
      sacc[k] += __shfl_down(sacc[k], off);
      qacc[k] += __shfl_down(qacc[k], off);
    }
  }
  __shared__ float red[2][4][4][8];  // [s|q][wave][s][k]
  if (lane < 4) {
#pragma unroll
    for (int k = 0; k < 8; ++k) {
      red[0][wv][lane][k] = sacc[k];
      red[1][wv][lane][k] = qacc[k];
    }
  }
  __syncthreads();
  if (tid < 32) {                    // c = tid
    int ss = tid >> 3, k = tid & 7;
    float S = 0.f, Q = 0.f;
#pragma unroll
    for (int w = 0; w < 4; ++w) {
      S += red[0][w][ss][k];
      Q += red[1][w][ss][k];
    }
    int idx = ((b * 16 + p) * 2 + h) * 32 + tid;
    ws_sum[idx] = S;
    ws_sq[idx] = Q;
  }
}

// ---------------- Kernel 2: pack conv_w into MFMA A-fragments ----------------
__global__ __launch_bounds__(256) void weights_prep(
    const float* __restrict__ conv_w, unsigned short* __restrict__ wfrag) {
  int idx = blockIdx.x * 256 + threadIdx.x;
  if (idx >= 18 * 64) return;
  int lane = idx & 63;
  int th = idx >> 6;                 // t*2 + h
  int t = th >> 1, h = th & 1;
  int dy = t / 3, dx = t - dy * 3;
  int oc = h * 16 + (lane & 15);
  int ic0 = (lane >> 4) * 8;
#pragma unroll
  for (int j = 0; j < 8; ++j) {
    float w = conv_w[((oc * 32 + ic0 + j) * 3 + dy) * 3 + dx];
    wfrag[(size_t)idx * 8 + j] = (unsigned short)f2bf(w);
  }
}

// ---------------- Kernel 3: double-buffered DMA conv ------------------------
// 2048 blocks = (b, p, hq): 16 output rows (4 tiles x 4 rows).
// LDS: 2 x [6 rows][64 cols][32 ic] bf16 = 49152 B -> 3 blocks/CU.
__global__ __launch_bounds__(256) void conv_dbuf(
    const unsigned short* __restrict__ xc,
    const unsigned short* __restrict__ wfrag,
    const float* __restrict__ conv_b, const float* __restrict__ prelu_a,
    const float* __restrict__ ws_sum, const float* __restrict__ ws_sq,
    const float* __restrict__ gamma, const float* __restrict__ beta,
    float* __restrict__ out) {
  __shared__ short ldsbuf[2 * 6 * 64 * 32];   // 49152 B
  __shared__ float abuf[64];

  int blk0 = blockIdx.x;             // 2048; chunked XCD swizzle (2048%8==0)
  int blk = (blk0 & 7) * 256 + (blk0 >> 3);
  int hq = blk & 3;
  int p = (blk >> 2) & 15;
  int b = blk >> 6;
  int R = p >> 2, Cc = p & 3;
  int r0 = hq * 16;
  int tid = threadIdx.x;
  int lane = tid & 63;
  int wv = tid >> 6;
  int l15 = lane & 15, l4 = lane >> 4;
  float pa = prelu_a[0];

  int s = tid & 3;                   // norm-pass ic-slice
  int c4 = (tid >> 2) & 15;          // norm-pass col-quad
  int rgrp = tid >> 6;               // norm-pass row group
  int ic0 = s * 8;

  const unsigned short* xcp = xc + ((size_t)(b * 16 + p)) * 131072;
  const short8 z8 = {0, 0, 0, 0, 0, 0, 0, 0};
  short* bufA = ldsbuf;
  short* bufB = ldsbuf + 12288;

  // ---- stage (DMA issue) for one tile: 6 rows x 4 quarters; wave wv owns
  // quarter wv of every row. Wave-uniform LDS dest, per-lane global src.
  auto stage_tile = [&](short* buf, int t) {
#pragma unroll
    for (int sr = 0; sr < 6; ++sr) {
      int lr = r0 + t * 4 - 1 + sr;
      short* dst = buf + (sr * 64 + wv * 16) * 32;
      if ((unsigned)lr < 64u) {
        const unsigned short* g =
            xcp + ((size_t)(lr * 64 + wv * 16) * 4) * 8 + (size_t)lane * 8;
        dma16(g, dst);
      } else {
        *reinterpret_cast<short8*>(dst + lane * 8) = z8;
      }
    }
  };

  // ---- in-LDS norm+PReLU (raw bf16 -> normalized bf16, in place)
  auto norm_tile = [&](short* buf, int t, const float* a_r, const float* b_r) {
#pragma unroll
    for (int rep = 0; rep < 2; ++rep) {
      int sr = rgrp + rep * 4;
      if (sr < 6) {
        int lr = r0 + t * 4 - 1 + sr;
        if ((unsigned)lr < 64u) {
#pragma unroll
          for (int j = 0; j < 4; ++j) {
            int col = c4 * 4 + j;
            int slot = (s + (col >> 1)) & 3;
            short8* gp = reinterpret_cast<short8*>(
                buf + (sr * 64 + col) * 32 + slot * 8);
            short8 pk = *gp;
#pragma unroll
            for (int k = 0; k < 8; ++k) {
              float e = fmaf(a_r[k], bf2f(pk[k]), b_r[k]);
              e = e > 0.f ? e : pa * e;
              pk[k] = f2bf(e);
            }
            *gp = pk;
          }
        }
      }
    }
  };

  // ---- prologue: issue tile-0 DMA, then finalize stats while it flies
  stage_tile(bufA, 0);

  bf16x8 wf[18];
#pragma unroll
  for (int th = 0; th < 18; ++th) {
    short8 sv =
        *reinterpret_cast<const short8*>(wfrag + ((size_t)th * 64 + lane) * 8);
    wf[th] = __builtin_bit_cast(bf16x8, sv);
  }
  f32x4 bias0, bias1;
#pragma unroll
  for (int i = 0; i < 4; ++i) {
    bias0[i] = conv_b[l4 * 4 + i];
    bias1[i] = conv_b[16 + l4 * 4 + i];
  }

  if (tid < 32) {                    // per-channel scale/shift for region p
    int c = tid;
    float S = 0.f, Q = 0.f;
#pragma unroll
    for (int bb = 0; bb < 32; ++bb) {
#pragma unroll
      for (int hh = 0; hh < 2; ++hh) {
        int idx = ((bb * 16 + p) * 2 + hh) * 32 + c;
        S += ws_sum[idx];
        Q += ws_sq[idx];
      }
    }
    const float inv = 1.0f / 131072.0f;
    float mean = S * inv;
    float var = Q * inv - mean * mean;
    float rstd = rsqrtf(var + EPS);
    float a = rstd * gamma[c];
    abuf[c] = a;
    abuf[32 + c] = beta[c] - mean * a;
  }
  __syncthreads();                   // drains tile-0 DMA + abuf visible

  float a_r[8], b_r[8];
#pragma unroll
  for (int j = 0; j < 8; ++j) {
    a_r[j] = abuf[ic0 + j];
    b_r[j] = abuf[32 + ic0 + j];
  }
  norm_tile(bufA, 0, a_r, b_r);
  __syncthreads();

  // ---- main loop: 4 tiles of 4 rows, DMA(t+1) in flight during compute(t)
  for (int t = 0; t < 4; ++t) {
    if (t < 3) stage_tile(bufB, t + 1);

    // compute tile t from bufA: wave wv does row wv's 4 col-blocks
#pragma unroll
    for (int g = 0; g < 4; ++g) {
      int r = wv;                    // one output row per wave
      int c0 = g * 16;
      f32x4 acc0 = bias0, acc1 = bias1;
#pragma unroll
      for (int t9 = 0; t9 < 9; ++t9) {
        const int dy = t9 / 3, dx = t9 - dy * 3;
        int sr = r + dy;             // 0..5
        int col_in = c0 + l15 + dx - 1;
        int colc = col_in & 63;
        int slot = (l4 + (colc >> 1)) & 3;
        short8 sv = *reinterpret_cast<const short8*>(
            bufA + (sr * 64 + colc) * 32 + slot * 8);
        if (dx == 0 && c0 == 0 && l15 == 0) sv = z8;     // col -1 pad
        if (dx == 2 && c0 == 48 && l15 == 15) sv = z8;   // col 64 pad
        bf16x8 bv = __builtin_bit_cast(bf16x8, sv);
        acc0 = __builtin_amdgcn_mfma_f32_16x16x32_bf16(wf[t9 * 2], bv, acc0,
                                                       0, 0, 0);
        acc1 = __builtin_amdgcn_mfma_f32_16x16x32_bf16(wf[t9 * 2 + 1], bv,
                                                       acc1, 0, 0, 0);
      }
      int grow = R * 64 + r0 + t * 4 + r;
      int gcol = Cc * 64 + c0 + l15;
      float* ob = out + (size_t)b * 2097152 + (size_t)grow * 256 + gcol;
#pragma unroll
      for (int i = 0; i < 4; ++i) {
        ob[(size_t)(l4 * 4 + i) * 65536] = acc0[i];
        ob[(size_t)(16 + l4 * 4 + i) * 65536] = acc1[i];
      }
    }
    __syncthreads();                 // drains DMA(t+1) + compute reads done
    if (t < 3) norm_tile(bufB, t + 1, a_r, b_r);
    __syncthreads();
    short* tmp = bufA; bufA = bufB; bufB = tmp;
  }
}

extern "C" void kernel_launch(void* const* d_in, const int* in_sizes, int n_in,
                              void* d_out, int out_size, void* d_ws,
                              size_t ws_size, hipStream_t stream) {
  const float* x = (const float*)d_in[0];
  const float* gamma = (const float*)d_in[1];
  const float* beta = (const float*)d_in[2];
  const float* prelu_a = (const float*)d_in[3];
  const float* conv_w = (const float*)d_in[4];
  const float* conv_b = (const float*)d_in[5];
  float* out = (float*)d_out;

  float* ws = (float*)d_ws;
  float* ws_sum = ws;                          // 32768 floats
  float* ws_sq = ws + 32768;                   // 32768 floats
  unsigned short* wfrag = (unsigned short*)(ws + 65536);   // 9216 shorts
  unsigned short* xc = (unsigned short*)(ws + 70144);      // 67108864 shorts

  weights_prep<<<5, 256, 0, stream>>>(conv_w, wfrag);
  stats_copy<<<1024, 256, 0, stream>>>(x, ws_sum, ws_sq, xc);
  conv_dbuf<<<2048, 256, 0, stream>>>(xc, wfrag, conv_b, prelu_a, ws_sum,
                                      ws_sq, gamma, beta, out);
}

// Round 13
// 190.083 us; speedup vs baseline: 1.3490x; 1.1694x over previous
//
#include <hip/hip_runtime.h>
#include <hip/hip_bf16.h>

// B=32, C=32, H=W=256, regions 4x4 of 64x64.
// Round 13: wave-specialized conv. Block = (b,p), 512 threads.
// Waves 4-7 (producers): global load x -> norm+PReLU -> bf16 -> ds_write
// into buf[(t+1)&1]. Waves 0-3 (consumers): ds_read buf[t&1] -> MFMA ->
// store. One barrier per tile; producer loads are consumed pre-barrier so
// the vmcnt drain is free. LDS dbuf 2x[10][64][32] bf16 = 80KB (1 block/CU;
// overlap is structural within the block, not occupancy-dependent).

#define EPS 1e-5f

typedef float f32x4 __attribute__((ext_vector_type(4)));
typedef __bf16 bf16x8 __attribute__((ext_vector_type(8)));
typedef short short8 __attribute__((ext_vector_type(8)));

__device__ inline short f2bf(float f) {
  union { __hip_bfloat16 h; short s; } u;
  u.h = __float2bfloat16(f);
  return u.s;
}

// ---------------- Kernel 1: per-(b,c) plane stats, contiguous sweep ----------
__global__ __launch_bounds__(256) void stats_partial(
    const float* __restrict__ x, float* __restrict__ ws_sum,
    float* __restrict__ ws_sq) {
  int plane = blockIdx.x;            // b*32 + c
  const float* base = x + (size_t)plane * 65536;
  int t = threadIdx.x;
  float s[4] = {0.f, 0.f, 0.f, 0.f}, q[4] = {0.f, 0.f, 0.f, 0.f};
#pragma unroll
  for (int R = 0; R < 4; ++R) {
#pragma unroll
    for (int ii = 0; ii < 16; ++ii) {
      int idx4 = (R * 16 + ii) * 256 + t;     // float4 index
      float4 v = *reinterpret_cast<const float4*>(base + (size_t)idx4 * 4);
      s[R] += (v.x + v.y) + (v.z + v.w);
      q[R] += (v.x * v.x + v.y * v.y) + (v.z * v.z + v.w * v.w);
    }
  }
#pragma unroll
  for (int R = 0; R < 4; ++R) {
#pragma unroll
    for (int off = 8; off; off >>= 1) {
      s[R] += __shfl_down(s[R], off);
      q[R] += __shfl_down(q[R], off);
    }
  }
  __shared__ float red[2][4][4][4];  // [s|q][wave][Cc][R]
  int lane = t & 63, wv = t >> 6;
  if ((lane & 15) == 0) {
    int Cc = lane >> 4;
#pragma unroll
    for (int R = 0; R < 4; ++R) {
      red[0][wv][Cc][R] = s[R];
      red[1][wv][Cc][R] = q[R];
    }
  }
  __syncthreads();
  if (t < 16) {                      // t == p
    int R = t >> 2, Cc = t & 3;
    float S = 0.f, Q = 0.f;
#pragma unroll
    for (int w = 0; w < 4; ++w) {
      S += red[0][w][Cc][R];
      Q += red[1][w][Cc][R];
    }
    ws_sum[plane * 16 + t] = S;
    ws_sq[plane * 16 + t] = Q;
  }
}

// ---------------- Kernel 2: pack conv_w into MFMA A-fragments ----------------
__global__ __launch_bounds__(256) void weights_prep(
    const float* __restrict__ conv_w, unsigned short* __restrict__ wfrag) {
  int idx = blockIdx.x * 256 + threadIdx.x;
  if (idx >= 18 * 64) return;
  int lane = idx & 63;
  int th = idx >> 6;                 // t*2 + h
  int t = th >> 1, h = th & 1;
  int dy = t / 3, dx = t - dy * 3;
  int oc = h * 16 + (lane & 15);
  int ic0 = (lane >> 4) * 8;
#pragma unroll
  for (int j = 0; j < 8; ++j) {
    float w = conv_w[((oc * 32 + ic0 + j) * 3 + dy) * 3 + dx];
    wfrag[(size_t)idx * 8 + j] = (unsigned short)f2bf(w);
  }
}

// ---------------- Kernel 3: wave-specialized producer/consumer conv ---------
// 512 blocks = (b, p). 512 threads. 8 tiles of 8 output rows.
__global__ __launch_bounds__(512) void conv_ws(
    const float* __restrict__ x, const unsigned short* __restrict__ wfrag,
    const float* __restrict__ conv_b, const float* __restrict__ prelu_a,
    const float* __restrict__ ws_sum, const float* __restrict__ ws_sq,
    const float* __restrict__ gamma, const float* __restrict__ beta,
    float* __restrict__ out) {
  __shared__ short buf2[2][10 * 64 * 32];   // 81920 B
  __shared__ float abuf[64];

  int blk0 = blockIdx.x;             // 512 blocks; chunked XCD swizzle
  int blk = (blk0 & 7) * 64 + (blk0 >> 3);
  int p = blk & 15;
  int b = blk >> 4;
  int R = p >> 2, Cc = p & 3;
  int tid = threadIdx.x;
  int lane = tid & 63;
  bool producer = tid >= 256;
  int t0 = tid & 255;                // role-local id
  float pa = prelu_a[0];

  // ---- local finalize: per-channel scale/shift for region p
  if (tid < 32) {
    int c = tid;
    float S = 0.f, Q = 0.f;
#pragma unroll
    for (int bb = 0; bb < 32; ++bb) {
      int idx = (bb * 32 + c) * 16 + p;
      S += ws_sum[idx];
      Q += ws_sq[idx];
    }
    const float inv = 1.0f / 131072.0f;
    float mean = S * inv;
    float var = Q * inv - mean * mean;
    float rstd = rsqrtf(var + EPS);
    float a = rstd * gamma[c];
    abuf[c] = a;
    abuf[32 + c] = beta[c] - mean * a;
  }
  __syncthreads();

  // ---- producer decomposition (t0: s = ic-slice, c4 = col-quad, srb = row)
  int s = (t0 >> 4) & 3;
  int c4 = t0 & 15;
  int srb = t0 >> 6;
  int ic0 = s * 8;
  float a_r[8], b_r[8];
#pragma unroll
  for (int j = 0; j < 8; ++j) {
    a_r[j] = abuf[ic0 + j];
    b_r[j] = abuf[32 + ic0 + j];
  }

  auto stage_load = [&](f32x4(&vv)[8], int sr, int h0) {
    int lr = h0 - 1 + sr;
#pragma unroll
    for (int kk = 0; kk < 8; ++kk) vv[kk] = f32x4{0.f, 0.f, 0.f, 0.f};
    if ((unsigned)lr < 64u) {
      const float* xp =
          x + (((size_t)(b * 32 + ic0) * 256 + R * 64 + lr) * 256) + Cc * 64 +
          c4 * 4;
#pragma unroll
      for (int kk = 0; kk < 8; ++kk)
        vv[kk] = *reinterpret_cast<const f32x4*>(xp + (size_t)kk * 65536);
    }
  };
  auto stage_write = [&](short* buf, const f32x4(&vv)[8], int sr) {
#pragma unroll
    for (int j = 0; j < 4; ++j) {
      short8 pk;
#pragma unroll
      for (int kk = 0; kk < 8; ++kk) {
        float e = fmaf(a_r[kk], vv[kk][j], b_r[kk]);
        e = e > 0.f ? e : pa * e;
        pk[kk] = f2bf(e);
      }
      int col = c4 * 4 + j;
      int slot = (s + (col >> 1)) & 3;
      *reinterpret_cast<short8*>(&buf[(sr * 64 + col) * 32 + slot * 8]) = pk;
    }
  };
  auto stage_tile = [&](short* buf, int t) {  // 10 rows of tile t
    int h0 = t * 8;
    f32x4 va[8], vb[8], vc[8];
    stage_load(va, srb, h0);
    stage_load(vb, srb + 4, h0);
    stage_write(buf, va, srb);
    if (t0 < 128) stage_load(vc, srb + 8, h0);
    stage_write(buf, vb, srb + 4);
    if (t0 < 128) stage_write(buf, vc, srb + 8);
  };

  // ---- consumer constants
  int l15 = lane & 15, l4 = lane >> 4;
  int wv = t0 >> 6;                  // 0..3 for consumers
  bf16x8 wf[18];
  f32x4 bias0, bias1;
  if (!producer) {
#pragma unroll
    for (int th = 0; th < 18; ++th) {
      short8 sv = *reinterpret_cast<const short8*>(
          wfrag + ((size_t)th * 64 + lane) * 8);
      wf[th] = __builtin_bit_cast(bf16x8, sv);
    }
#pragma unroll
    for (int i = 0; i < 4; ++i) {
      bias0[i] = conv_b[l4 * 4 + i];
      bias1[i] = conv_b[16 + l4 * 4 + i];
    }
  }
  const short8 z8 = {0, 0, 0, 0, 0, 0, 0, 0};

  auto compute_tile = [&](const short* buf, int t) {
    int h0 = t * 8;
    for (int g = 0; g < 8; ++g) {
      int gi = wv * 8 + g;           // 32 groups: r = gi>>2, cblk = gi&3
      int r = gi >> 2;
      int c0 = (gi & 3) * 16;
      f32x4 acc0 = bias0, acc1 = bias1;
#pragma unroll
      for (int t9 = 0; t9 < 9; ++t9) {
        const int dy = t9 / 3, dx = t9 - dy * 3;
        int sr = r + dy;
        int col_in = c0 + l15 + dx - 1;
        int colc = col_in & 63;
        int slot = (l4 + (colc >> 1)) & 3;
        short8 sv = *reinterpret_cast<const short8*>(
            &buf[(sr * 64 + colc) * 32 + slot * 8]);
        if (dx == 0 && c0 == 0 && l15 == 0) sv = z8;     // col -1 pad
        if (dx == 2 && c0 == 48 && l15 == 15) sv = z8;   // col 64 pad
        bf16x8 bv = __builtin_bit_cast(bf16x8, sv);
        acc0 = __builtin_amdgcn_mfma_f32_16x16x32_bf16(wf[t9 * 2], bv, acc0,
                                                       0, 0, 0);
        acc1 = __builtin_amdgcn_mfma_f32_16x16x32_bf16(wf[t9 * 2 + 1], bv,
                                                       acc1, 0, 0, 0);
      }
      int grow = R * 64 + h0 + r;
      int gcol = Cc * 64 + c0 + l15;
      float* ob = out + (size_t)b * 2097152 + (size_t)grow * 256 + gcol;
#pragma unroll
      for (int i = 0; i < 4; ++i) {
        ob[(size_t)(l4 * 4 + i) * 65536] = acc0[i];
        ob[(size_t)(16 + l4 * 4 + i) * 65536] = acc1[i];
      }
    }
  };

  // ---- prologue: producers stage tile 0 into buf[0]
  if (producer) stage_tile(buf2[0], 0);
  __syncthreads();

  // ---- main loop: producers fill buf[(t+1)&1] while consumers eat buf[t&1]
  for (int t = 0; t < 8; ++t) {
    if (producer) {
      if (t < 7) stage_tile(buf2[(t + 1) & 1], t + 1);
    } else {
      compute_tile(buf2[t & 1], t);
    }
    __syncthreads();
  }
}

extern "C" void kernel_launch(void* const* d_in, const int* in_sizes, int n_in,
                              void* d_out, int out_size, void* d_ws,
                              size_t ws_size, hipStream_t stream) {
  const float* x = (const float*)d_in[0];
  const float* gamma = (const float*)d_in[1];
  const float* beta = (const float*)d_in[2];
  const float* prelu_a = (const float*)d_in[3];
  const float* conv_w = (const float*)d_in[4];
  const float* conv_b = (const float*)d_in[5];
  float* out = (float*)d_out;

  float* ws = (float*)d_ws;
  float* ws_sum = ws;                          // 16384 floats
  float* ws_sq = ws + 16384;                   // 16384
  unsigned short* wfrag = (unsigned short*)(ws + 32768);   // 9216 shorts

  weights_prep<<<5, 256, 0, stream>>>(conv_w, wfrag);
  stats_partial<<<1024, 256, 0, stream>>>(x, ws_sum, ws_sq);
  conv_ws<<<512, 512, 0, stream>>>(x, wfrag, conv_b, prelu_a, ws_sum, ws_sq,
                                   gamma, beta, out);
}

// Round 14
// 172.458 us; speedup vs baseline: 1.4868x; 1.1022x over previous
//
#include <hip/hip_runtime.h>
#include <hip/hip_bf16.h>

// B=32, C=32, H=W=256, regions 4x4 of 64x64.
// Round 14: identical to round 8 (best, 190us) EXCEPT out-stores are
// non-temporal (nt hint). Theory: x (256MB) is L3-resident after the stats
// pass; conv's out-writes were evicting it (conv FETCH=194MB). nt stores
// keep x in L3 -> conv reads become L3 hits.

#define EPS 1e-5f

typedef float f32x4 __attribute__((ext_vector_type(4)));
typedef __bf16 bf16x8 __attribute__((ext_vector_type(8)));
typedef short short8 __attribute__((ext_vector_type(8)));

__device__ inline short f2bf(float f) {
  union { __hip_bfloat16 h; short s; } u;
  u.h = __float2bfloat16(f);
  return u.s;
}

// ---------------- Kernel 1: per-(b,c) plane stats, contiguous sweep ----------
__global__ __launch_bounds__(256) void stats_partial(
    const float* __restrict__ x, float* __restrict__ ws_sum,
    float* __restrict__ ws_sq) {
  int plane = blockIdx.x;            // b*32 + c
  const float* base = x + (size_t)plane * 65536;
  int t = threadIdx.x;
  float s[4] = {0.f, 0.f, 0.f, 0.f}, q[4] = {0.f, 0.f, 0.f, 0.f};
#pragma unroll
  for (int R = 0; R < 4; ++R) {
#pragma unroll
    for (int ii = 0; ii < 16; ++ii) {
      int idx4 = (R * 16 + ii) * 256 + t;     // float4 index
      float4 v = *reinterpret_cast<const float4*>(base + (size_t)idx4 * 4);
      s[R] += (v.x + v.y) + (v.z + v.w);
      q[R] += (v.x * v.x + v.y * v.y) + (v.z * v.z + v.w * v.w);
    }
  }
#pragma unroll
  for (int R = 0; R < 4; ++R) {
#pragma unroll
    for (int off = 8; off; off >>= 1) {
      s[R] += __shfl_down(s[R], off);
      q[R] += __shfl_down(q[R], off);
    }
  }
  __shared__ float red[2][4][4][4];  // [s|q][wave][Cc][R]
  int lane = t & 63, wv = t >> 6;
  if ((lane & 15) == 0) {
    int Cc = lane >> 4;
#pragma unroll
    for (int R = 0; R < 4; ++R) {
      red[0][wv][Cc][R] = s[R];
      red[1][wv][Cc][R] = q[R];
    }
  }
  __syncthreads();
  if (t < 16) {                      // t == p
    int R = t >> 2, Cc = t & 3;
    float S = 0.f, Q = 0.f;
#pragma unroll
    for (int w = 0; w < 4; ++w) {
      S += red[0][w][Cc][R];
      Q += red[1][w][Cc][R];
    }
    ws_sum[plane * 16 + t] = S;
    ws_sq[plane * 16 + t] = Q;
  }
}

// ---------------- Kernel 2: pack conv_w into MFMA A-fragments ----------------
__global__ __launch_bounds__(256) void weights_prep(
    const float* __restrict__ conv_w, unsigned short* __restrict__ wfrag) {
  int idx = blockIdx.x * 256 + threadIdx.x;
  if (idx >= 18 * 64) return;
  int lane = idx & 63;
  int th = idx >> 6;                 // t*2 + h
  int t = th >> 1, h = th & 1;
  int dy = t / 3, dx = t - dy * 3;
  int oc = h * 16 + (lane & 15);
  int ic0 = (lane >> 4) * 8;
#pragma unroll
  for (int j = 0; j < 8; ++j) {
    float w = conv_w[((oc * 32 + ic0 + j) * 3 + dy) * 3 + dx];
    wfrag[(size_t)idx * 8 + j] = (unsigned short)f2bf(w);
  }
}

// ---------------- Kernel 3: finalize + normalize+prelu -> LDS -> MFMA -------
// block = (b, p, rt): 8 output rows x 64 cols of one region. 4 waves.
// LDS: [10 rows][64 cols][4 slots x 8 ic] bf16, slot swizzled by (col>>1)&3.
__global__ __launch_bounds__(256) void conv_mfma(
    const float* __restrict__ x, const unsigned short* __restrict__ wfrag,
    const float* __restrict__ conv_b, const float* __restrict__ prelu_a,
    const float* __restrict__ ws_sum, const float* __restrict__ ws_sq,
    const float* __restrict__ gamma, const float* __restrict__ beta,
    float* __restrict__ out) {
  __shared__ short lds_y[10 * 64 * 32];  // 40960 B -> 4 blocks/CU

  int blk0 = blockIdx.x;             // 4096 blocks; chunked XCD swizzle
  int blk = (blk0 & 7) * 512 + (blk0 >> 3);
  int rt = blk & 7;
  int p = (blk >> 3) & 15;
  int b = blk >> 7;
  int R = p >> 2, Cc = p & 3;
  int h0 = rt * 8;
  int tid = threadIdx.x;
  int lane = tid & 63;
  float pa = prelu_a[0];

  // ---- local finalize: per-channel scale/shift for region p (32 threads)
  float* abuf = (float*)lds_y;       // [0..31]=a, [32..63]=b; freed below
  if (tid < 32) {
    int c = tid;
    float S = 0.f, Q = 0.f;
#pragma unroll
    for (int bb = 0; bb < 32; ++bb) {
      int idx = (bb * 32 + c) * 16 + p;
      S += ws_sum[idx];
      Q += ws_sq[idx];
    }
    const float inv = 1.0f / 131072.0f;
    float mean = S * inv;
    float var = Q * inv - mean * mean;
    float rstd = rsqrtf(var + EPS);
    float a = rstd * gamma[c];
    abuf[c] = a;
    abuf[32 + c] = beta[c] - mean * a;
  }
  __syncthreads();

  // per-thread-fixed staging decomposition
  int s = (tid >> 4) & 3;            // ic-slice
  int c4 = tid & 15;                 // col-quad
  int srb = tid >> 6;                // base staged-row
  int ic0 = s * 8;

  float a_r[8], b_r[8];
#pragma unroll
  for (int j = 0; j < 8; ++j) {
    a_r[j] = abuf[ic0 + j];
    b_r[j] = abuf[32 + ic0 + j];
  }
  __syncthreads();                   // abuf consumed; LDS free for staging

  // ---- staging helpers
  auto stage_load = [&](f32x4(&vv)[8], int sr) {
    int lr = h0 - 1 + sr;
#pragma unroll
    for (int kk = 0; kk < 8; ++kk) vv[kk] = f32x4{0.f, 0.f, 0.f, 0.f};
    if ((unsigned)lr < 64u) {
      const float* xp =
          x + (((size_t)(b * 32 + ic0) * 256 + R * 64 + lr) * 256) + Cc * 64 +
          c4 * 4;
#pragma unroll
      for (int kk = 0; kk < 8; ++kk)
        vv[kk] = *reinterpret_cast<const f32x4*>(xp + (size_t)kk * 65536);
    }
  };
  auto stage_write = [&](const f32x4(&vv)[8], int sr) {
#pragma unroll
    for (int j = 0; j < 4; ++j) {
      short8 pk;
#pragma unroll
      for (int kk = 0; kk < 8; ++kk) {
        float e = fmaf(a_r[kk], vv[kk][j], b_r[kk]);
        e = e > 0.f ? e : pa * e;
        pk[kk] = f2bf(e);
      }
      int col = c4 * 4 + j;
      int slot = (s + (col >> 1)) & 3;
      *reinterpret_cast<short8*>(&lds_y[(sr * 64 + col) * 32 + slot * 8]) = pk;
    }
  };

  // ---- 3-deep pipelined staging: rows srb, srb+4, srb+8(tid<128)
  {
    f32x4 va[8], vb[8], vc[8];
    stage_load(va, srb);             // 8 loads in flight
    stage_load(vb, srb + 4);         // 16 loads in flight
    stage_write(va, srb);
    if (tid < 128) stage_load(vc, srb + 8);
    stage_write(vb, srb + 4);
    if (tid < 128) stage_write(vc, srb + 8);
  }
  __syncthreads();

  // ---- weight fragments + bias (post-barrier: lower VGPR during staging)
  bf16x8 wf[18];
#pragma unroll
  for (int th = 0; th < 18; ++th) {
    short8 sv =
        *reinterpret_cast<const short8*>(wfrag + ((size_t)th * 64 + lane) * 8);
    wf[th] = __builtin_bit_cast(bf16x8, sv);
  }
  int l15 = lane & 15, l4 = lane >> 4;
  f32x4 bias0, bias1;
#pragma unroll
  for (int i = 0; i < 4; ++i) {
    bias0[i] = conv_b[l4 * 4 + i];
    bias1[i] = conv_b[16 + l4 * 4 + i];
  }

  // ---- MFMA: each wave does 8 groups of (row r, 16-col block)
  int wv = tid >> 6;
  const short8 z8 = {0, 0, 0, 0, 0, 0, 0, 0};
  for (int g = 0; g < 8; ++g) {
    int gi = wv * 8 + g;
    int r = gi >> 2;
    int c0 = (gi & 3) * 16;
    f32x4 acc0 = bias0, acc1 = bias1;
#pragma unroll
    for (int t9 = 0; t9 < 9; ++t9) {
      const int dy = t9 / 3, dx = t9 - dy * 3;
      int sr = r + dy;
      int col_in = c0 + l15 + dx - 1;     // -1..64 possible at edges
      int colc = col_in & 63;
      int slot = (l4 + (colc >> 1)) & 3;
      short8 sv = *reinterpret_cast<const short8*>(
          &lds_y[(sr * 64 + colc) * 32 + slot * 8]);
      if (dx == 0) {
        if (c0 == 0 && l15 == 0) sv = z8;     // col -1 -> zero pad
      }
      if (dx == 2) {
        if (c0 == 48 && l15 == 15) sv = z8;   // col 64 -> zero pad
      }
      bf16x8 bv = __builtin_bit_cast(bf16x8, sv);
      acc0 = __builtin_amdgcn_mfma_f32_16x16x32_bf16(wf[t9 * 2], bv, acc0, 0, 0, 0);
      acc1 = __builtin_amdgcn_mfma_f32_16x16x32_bf16(wf[t9 * 2 + 1], bv, acc1, 0, 0, 0);
    }
    int grow = R * 64 + h0 + r;
    int gcol = Cc * 64 + c0 + l15;
    float* ob = out + (size_t)b * 2097152 + (size_t)grow * 256 + gcol;
#pragma unroll
    for (int i = 0; i < 4; ++i) {
      __builtin_nontemporal_store(acc0[i], &ob[(size_t)(l4 * 4 + i) * 65536]);
      __builtin_nontemporal_store(acc1[i],
                                  &ob[(size_t)(16 + l4 * 4 + i) * 65536]);
    }
  }
}

extern "C" void kernel_launch(void* const* d_in, const int* in_sizes, int n_in,
                              void* d_out, int out_size, void* d_ws,
                              size_t ws_size, hipStream_t stream) {
  const float* x = (const float*)d_in[0];
  const float* gamma = (const float*)d_in[1];
  const float* beta = (const float*)d_in[2];
  const float* prelu_a = (const float*)d_in[3];
  const float* conv_w = (const float*)d_in[4];
  const float* conv_b = (const float*)d_in[5];
  float* out = (float*)d_out;

  float* ws = (float*)d_ws;
  float* ws_sum = ws;                          // 16384 floats
  float* ws_sq = ws + 16384;                   // 16384
  unsigned short* wfrag = (unsigned short*)(ws + 32768);   // 18*64*8 shorts

  weights_prep<<<5, 256, 0, stream>>>(conv_w, wfrag);
  stats_partial<<<1024, 256, 0, stream>>>(x, ws_sum, ws_sq);
  conv_mfma<<<4096, 256, 0, stream>>>(x, wfrag, conv_b, prelu_a, ws_sum, ws_sq,
                                      gamma, beta, out);
}